// Round 1
// baseline (2630.250 us; speedup 1.0000x reference)
//
#include <hip/hip_runtime.h>

#define NN 100000
#define FF 128
#define HH 64
#define CC 16
#define EE 1000000

__device__ __forceinline__ float fsig(float t)  { return 1.0f/(1.0f+__expf(-t)); }
__device__ __forceinline__ float ftanh(float t) { return 1.0f - 2.0f/(__expf(2.0f*t)+1.0f); }

// ---- Combined weights: W1 = W_ih @ W_con1 [192x128], b1 = b_ih + W_ih @ b_con1 (same for 2)
__global__ void precomp_kernel(const float* __restrict__ W_ih, const float* __restrict__ b_ih,
                               const float* __restrict__ Wc1,  const float* __restrict__ bc1,
                               const float* __restrict__ Wc2,  const float* __restrict__ bc2,
                               float* __restrict__ W1, float* __restrict__ b1,
                               float* __restrict__ W2, float* __restrict__ b2)
{
    int idx = blockIdx.x*blockDim.x + threadIdx.x;
    const int total = 192*128;
    if (idx < total) {
        int j = idx >> 7, k = idx & 127;
        float s1 = 0.f, s2 = 0.f;
        for (int m=0; m<64; ++m) {
            float wih = W_ih[j*64+m];
            s1 += wih * Wc1[m*128+k];
            s2 += wih * Wc2[m*128+k];
        }
        W1[idx] = s1; W2[idx] = s2;
    } else if (idx < total + 192) {
        int j = idx - total;
        float s1 = b_ih[j], s2 = b_ih[j];
        for (int m=0; m<64; ++m) {
            float wih = W_ih[j*64+m];
            s1 += wih * bc1[m];
            s2 += wih * bc2[m];
        }
        b1[j] = s1; b2[j] = s2;
    }
}

// ---- h = x @ W_first^T + b   (K=128 -> M=64). Thread j holds W row j in VGPRs.
__global__ __launch_bounds__(256) void lin_first_kernel(
    const float* __restrict__ X, const float* __restrict__ W,
    const float* __restrict__ b, float* __restrict__ Y)
{
    const int j   = threadIdx.x & 63;
    const int sub = threadIdx.x >> 6;   // 4 nodes per block-iteration
    float Wr[128];
    #pragma unroll
    for (int k=0;k<128;k+=4) {
        float4 v = *(const float4*)&W[j*128+k];
        Wr[k]=v.x; Wr[k+1]=v.y; Wr[k+2]=v.z; Wr[k+3]=v.w;
    }
    const float bj = b[j];
    for (int n0 = blockIdx.x*4; n0 < NN; n0 += gridDim.x*4) {
        int n = n0 + sub;
        float acc = bj;
        const float4* xr = (const float4*)&X[(long)n*FF];
        #pragma unroll
        for (int k4=0;k4<32;++k4) {
            float4 v = xr[k4];
            acc += v.x*Wr[4*k4] + v.y*Wr[4*k4+1] + v.z*Wr[4*k4+2] + v.w*Wr[4*k4+3];
        }
        Y[(long)n*HH + j] = acc;
    }
}

// ---- segment_sum scatter: out[dst] += X[src]*w. One wave per edge, lane = feature.
__global__ __launch_bounds__(256) void prop_kernel(
    const float* __restrict__ X, const int* __restrict__ ei,
    const float* __restrict__ w, float* __restrict__ out)
{
    int e    = blockIdx.x*4 + (threadIdx.x>>6);
    int lane = threadIdx.x & 63;
    if (e >= EE) return;
    int   src = ei[e];
    int   dst = ei[EE + e];
    float wt  = w[e];
    float v = X[(long)src*HH + lane] * wt;
    atomicAdd(&out[(long)dst*HH + lane], v);
}

// ---- fused layer: gi = [x1|x2] @ Wg^T + bg (192), gh = h @ Whh^T + bhh (192),
//      then GRU gates -> Hout[n, 0:64]. Block = 192 threads, 1 node per iteration.
__global__ __launch_bounds__(192, 2) void layer_kernel(
    const float* __restrict__ X1, const float* __restrict__ X2,
    const float* __restrict__ H,
    const float* __restrict__ Wg,  const float* __restrict__ bg,
    const float* __restrict__ Whh, const float* __restrict__ bhh,
    float* __restrict__ Hout)
{
    const int j = threadIdx.x;  // 0..191
    float Wgr[128];
    #pragma unroll
    for (int k=0;k<128;k+=4) {
        float4 v = *(const float4*)&Wg[j*128+k];
        Wgr[k]=v.x; Wgr[k+1]=v.y; Wgr[k+2]=v.z; Wgr[k+3]=v.w;
    }
    float Whr[64];
    #pragma unroll
    for (int k=0;k<64;k+=4) {
        float4 v = *(const float4*)&Whh[j*64+k];
        Whr[k]=v.x; Whr[k+1]=v.y; Whr[k+2]=v.z; Whr[k+3]=v.w;
    }
    const float bgj = bg[j];
    const float bhj = bhh[j];
    __shared__ float gi_s[192];
    __shared__ float gh_s[192];
    for (int n = blockIdx.x; n < NN; n += gridDim.x) {
        float gi = bgj;
        float gh = bhj;
        const float4* x1r = (const float4*)&X1[(long)n*HH];
        const float4* x2r = (const float4*)&X2[(long)n*HH];
        const float4* hr  = (const float4*)&H [(long)n*HH];
        #pragma unroll
        for (int k4=0;k4<16;++k4) {
            float4 v = x1r[k4];
            gi += v.x*Wgr[4*k4] + v.y*Wgr[4*k4+1] + v.z*Wgr[4*k4+2] + v.w*Wgr[4*k4+3];
        }
        #pragma unroll
        for (int k4=0;k4<16;++k4) {
            float4 v = x2r[k4];
            gi += v.x*Wgr[64+4*k4] + v.y*Wgr[64+4*k4+1] + v.z*Wgr[64+4*k4+2] + v.w*Wgr[64+4*k4+3];
        }
        #pragma unroll
        for (int k4=0;k4<16;++k4) {
            float4 v = hr[k4];
            gh += v.x*Whr[4*k4] + v.y*Whr[4*k4+1] + v.z*Whr[4*k4+2] + v.w*Whr[4*k4+3];
        }
        gi_s[j] = gi;
        gh_s[j] = gh;
        __syncthreads();
        if (j < 64) {
            float r  = fsig(gi_s[j]      + gh_s[j]);
            float z  = fsig(gi_s[j+64]   + gh_s[j+64]);
            float nn = ftanh(gi_s[j+128] + r*gh_s[j+128]);
            float hv = H[(long)n*HH + j];
            Hout[(long)n*HH + j] = (1.0f - z)*nn + z*hv;
        }
        __syncthreads();
    }
}

// ---- y = x @ W^T + b (64->64). Safe to run in place (only the owning wave reads row n).
__global__ __launch_bounds__(256) void lin64_kernel(
    const float* X, const float* __restrict__ W,
    const float* __restrict__ b, float* Y)
{
    const int j   = threadIdx.x & 63;
    const int sub = threadIdx.x >> 6;
    float Wr[64];
    #pragma unroll
    for (int k=0;k<64;k+=4) {
        float4 v = *(const float4*)&W[j*64+k];
        Wr[k]=v.x; Wr[k+1]=v.y; Wr[k+2]=v.z; Wr[k+3]=v.w;
    }
    const float bj = b[j];
    for (int n0 = blockIdx.x*4; n0 < NN; n0 += gridDim.x*4) {
        int n = n0 + sub;
        float acc = bj;
        const float4* xr = (const float4*)&X[(long)n*HH];
        #pragma unroll
        for (int k4=0;k4<16;++k4) {
            float4 v = xr[k4];
            acc += v.x*Wr[4*k4] + v.y*Wr[4*k4+1] + v.z*Wr[4*k4+2] + v.w*Wr[4*k4+3];
        }
        Y[(long)n*HH + j] = acc;
    }
}

// ---- out = log_softmax(h2 @ W_out^T + b_out). 16 lanes per node; shfl reduce width 16.
__global__ __launch_bounds__(256) void out_kernel(
    const float* __restrict__ X, const float* __restrict__ W,
    const float* __restrict__ b, float* __restrict__ Y)
{
    const int c   = threadIdx.x & 15;
    const int sub = threadIdx.x >> 4;   // 16 nodes per block-iteration
    float Wr[64];
    #pragma unroll
    for (int k=0;k<64;k+=4) {
        float4 v = *(const float4*)&W[c*64+k];
        Wr[k]=v.x; Wr[k+1]=v.y; Wr[k+2]=v.z; Wr[k+3]=v.w;
    }
    const float bc = b[c];
    for (int n0 = blockIdx.x*16; n0 < NN; n0 += gridDim.x*16) {
        int n = n0 + sub;
        float acc = bc;
        const float4* xr = (const float4*)&X[(long)n*HH];
        #pragma unroll
        for (int k4=0;k4<16;++k4) {
            float4 v = xr[k4];
            acc += v.x*Wr[4*k4] + v.y*Wr[4*k4+1] + v.z*Wr[4*k4+2] + v.w*Wr[4*k4+3];
        }
        float m = acc;
        #pragma unroll
        for (int off=8; off>0; off>>=1) m = fmaxf(m, __shfl_xor(m, off, 16));
        float ex = __expf(acc - m);
        float s = ex;
        #pragma unroll
        for (int off=8; off>0; off>>=1) s += __shfl_xor(s, off, 16);
        Y[(long)n*CC + c] = acc - m - __logf(s);
    }
}

extern "C" void kernel_launch(void* const* d_in, const int* in_sizes, int n_in,
                              void* d_out, int out_size, void* d_ws, size_t ws_size,
                              hipStream_t stream)
{
    const float* x       = (const float*)d_in[0];
    const int*   ei      = (const int*)  d_in[1];
    const float* ew      = (const float*)d_in[2];
    const int*   ei_re   = (const int*)  d_in[3];
    const float* ew_re   = (const float*)d_in[4];
    const float* W_first = (const float*)d_in[5];
    const float* b_first = (const float*)d_in[6];
    const float* W_con1  = (const float*)d_in[7];
    const float* b_con1  = (const float*)d_in[8];
    const float* W_con2  = (const float*)d_in[9];
    const float* b_con2  = (const float*)d_in[10];
    const float* W_lin1  = (const float*)d_in[11];
    const float* b_lin1  = (const float*)d_in[12];
    const float* W_out   = (const float*)d_in[13];
    const float* b_out   = (const float*)d_in[14];
    const float* W_ih    = (const float*)d_in[15];
    const float* W_hh    = (const float*)d_in[16];
    const float* b_ih    = (const float*)d_in[17];
    const float* b_hh    = (const float*)d_in[18];
    float* out = (float*)d_out;

    float* h  = (float*)d_ws;              // [N,64]
    float* x1 = h  + (long)NN*HH;          // [N,64]
    float* x2 = x1 + (long)NN*HH;          // [N,64]
    float* hA = x2 + (long)NN*HH;          // [N,64] gate output / lin1 in-place / h2
    float* W1 = hA + (long)NN*HH;          // [192,128]
    float* W2 = W1 + 192*128;
    float* b1 = W2 + 192*128;
    float* b2 = b1 + 192;

    // 0) combined weights (needed before layer kernels only)
    precomp_kernel<<<(192*128 + 192 + 255)/256, 256, 0, stream>>>(
        W_ih, b_ih, W_con1, b_con1, W_con2, b_con2, W1, b1, W2, b2);

    // 1) h = x @ W_first^T + b_first
    lin_first_kernel<<<2048, 256, 0, stream>>>(x, W_first, b_first, h);

    // 2) layer-1 propagation
    hipMemsetAsync(x1, 0, (size_t)2*NN*HH*sizeof(float), stream);
    prop_kernel<<<EE/4, 256, 0, stream>>>(h, ei,    ew,    x1);
    prop_kernel<<<EE/4, 256, 0, stream>>>(h, ei_re, ew_re, x2);

    // 3) fused con1 + GRU -> hA
    layer_kernel<<<3072, 192, 0, stream>>>(x1, x2, h, W1, b1, W_hh, b_hh, hA);

    // 4) lin1 (in place on hA)
    lin64_kernel<<<2048, 256, 0, stream>>>(hA, W_lin1, b_lin1, hA);

    // 5) layer-2 propagation
    hipMemsetAsync(x1, 0, (size_t)2*NN*HH*sizeof(float), stream);
    prop_kernel<<<EE/4, 256, 0, stream>>>(hA, ei,    ew,    x1);
    prop_kernel<<<EE/4, 256, 0, stream>>>(hA, ei_re, ew_re, x2);

    // 6) fused con2 + GRU -> hA
    layer_kernel<<<3072, 192, 0, stream>>>(x1, x2, h, W2, b2, W_hh, b_hh, hA);

    // 7) W_out + log_softmax
    out_kernel<<<2048, 256, 0, stream>>>(hA, W_out, b_out, out);
}